// Round 1
// baseline (9.756 us; speedup 1.0000x reference)
//
#include <hip/hip_runtime.h>

// Partial trace of rho (8192x8192 fp32), D=2, N=13, keep qudits Q=(3,7,11).
// Big-endian digits: qudit q <-> bit (13-q); kept bit positions = {10, 6, 2}.
// out[a*8+b] = sum_t rho[(spread(t)|keep(a))*8192 + (spread(t)|keep(b))]
// Only 65536 of 67.1M elements contribute -> sparse gather, latency-bound.

__device__ __forceinline__ unsigned spread_traced(unsigned t) {
    // Scatter 10 bits of t into positions {0,1, 3,4,5, 7,8,9, 11,12}
    return (t & 0x003u)           // t[0:2)  -> bits 0..1
         | ((t & 0x01Cu) << 1)    // t[2:5)  -> bits 3..5
         | ((t & 0x0E0u) << 2)    // t[5:8)  -> bits 7..9
         | ((t & 0x300u) << 3);   // t[8:10) -> bits 11..12
}

__device__ __forceinline__ unsigned keep_bits(unsigned x) {
    // 3 bits of x -> positions 10 (MSB), 6, 2 (LSB)
    return ((x >> 2) & 1u) << 10 | ((x >> 1) & 1u) << 6 | (x & 1u) << 2;
}

__global__ void __launch_bounds__(256)
ptrace_kernel(const float* __restrict__ rho, float* __restrict__ out) {
    const int ab = blockIdx.x;            // 0..63, one output element per block
    const unsigned ka = keep_bits((unsigned)(ab >> 3));
    const unsigned kb = keep_bits((unsigned)(ab & 7));

    float sum = 0.0f;
    // 1024 traced configs over 256 threads -> 4 per thread
    for (unsigned t = threadIdx.x; t < 1024u; t += 256u) {
        const unsigned s = spread_traced(t);
        sum += rho[(s | ka) * 8192u + (s | kb)];
    }

    // wave64 shuffle reduction
    #pragma unroll
    for (int off = 32; off > 0; off >>= 1)
        sum += __shfl_down(sum, off, 64);

    __shared__ float ws[4];
    const int lane = threadIdx.x & 63;
    const int wid  = threadIdx.x >> 6;
    if (lane == 0) ws[wid] = sum;
    __syncthreads();
    if (threadIdx.x == 0)
        out[ab] = ws[0] + ws[1] + ws[2] + ws[3];
}

extern "C" void kernel_launch(void* const* d_in, const int* in_sizes, int n_in,
                              void* d_out, int out_size, void* d_ws, size_t ws_size,
                              hipStream_t stream) {
    const float* rho = (const float*)d_in[0];
    float* out = (float*)d_out;
    ptrace_kernel<<<64, 256, 0, stream>>>(rho, out);
}